// Round 5
// baseline (271.236 us; speedup 1.0000x reference)
//
#include <hip/hip_runtime.h>

// Problem constants (B, L, D, H) = (16, 512, 128, 8)
#define B_  16
#define L_  512
#define D_  128
#define H_  8
#define HD_ 1024   // H*D
#define NH_ 128    // H*B
#define M_  8192   // B*L

typedef unsigned short u16;
typedef __attribute__((ext_vector_type(8))) short s16x8;   // 8 bf16 = 4 VGPRs
typedef __attribute__((ext_vector_type(4))) float f32x4;   // MFMA accumulator

// ---------- bf16 helpers ----------
__device__ __forceinline__ float bf2f(u16 u) {
    union { unsigned u; float f; } x; x.u = ((unsigned)u) << 16; return x.f;
}
__device__ __forceinline__ u16 f2bf(float f) {
    unsigned u = __float_as_uint(f);
    return (u16)((u + 0x7FFFu + ((u >> 16) & 1u)) >> 16);   // RNE
}

// ---------------------------------------------------------------
// MFMA bt-core: C(64x64) = A(64xK) @ B(64xK)^T for one wave.
// A/B operand layout: row = lane&15, k = (lane>>4)*8 + j  (16B contiguous)
// C/D: col = lane&15, row = (lane>>4)*4 + reg   (m89/m91-verified)
// ---------------------------------------------------------------
__device__ __forceinline__ void mfma_bt64(const u16* __restrict__ A, int lda,
                                          const u16* __restrict__ B, int ldb,
                                          int K, int lane, f32x4 acc[4][4]) {
    const int mr = lane & 15, quad = lane >> 4;
    for (int k0 = 0; k0 < K; k0 += 32) {
        s16x8 av[4], bv[4];
#pragma unroll
        for (int i = 0; i < 4; i++)
            av[i] = *(const s16x8*)(A + (size_t)(i * 16 + mr) * lda + k0 + quad * 8);
#pragma unroll
        for (int j = 0; j < 4; j++)
            bv[j] = *(const s16x8*)(B + (size_t)(j * 16 + mr) * ldb + k0 + quad * 8);
#pragma unroll
        for (int i = 0; i < 4; i++)
#pragma unroll
            for (int j = 0; j < 4; j++)
                acc[i][j] = __builtin_amdgcn_mfma_f32_16x16x32_bf16(av[i], bv[j], acc[i][j], 0, 0, 0);
    }
}

// ---------------------------------------------------------------
// K0: detect float dtype (fp32 vs packed bf16) + mask dtype (i32 vs u8).
// ---------------------------------------------------------------
__global__ void k0_detect(const unsigned int* __restrict__ pad,
                          const unsigned int* __restrict__ xw,
                          int* __restrict__ flags) {
    __shared__ int sMask, sCnt;
    if (threadIdx.x == 0) { sMask = 0; sCnt = 0; }
    __syncthreads();
    int bad = 0;
#pragma unroll
    for (int i = 0; i < 4; i++) {
        unsigned u = pad[threadIdx.x * 4 + i];
        bad |= (u > 1u) ? 1 : 0;
    }
    int cnt = 0;
#pragma unroll
    for (int i = 0; i < 16; i++) {
        unsigned w = xw[threadIdx.x * 16 + i];
        unsigned e = (w >> 7) & 0xFFu;
        cnt += (e >= 100u && e <= 131u) ? 1 : 0;
    }
    if (bad) atomicOr(&sMask, 1);
    atomicAdd(&sCnt, cnt);
    __syncthreads();
    if (threadIdx.x == 0) {
        flags[0] = (sCnt > 2048) ? 1 : 0;   // 1 => floats are bf16
        flags[1] = sMask;                   // 1 => mask is uint8
    }
}

// ---------------------------------------------------------------
// Kprep_conv: normalize all float inputs to bf16 in ws.
// ---------------------------------------------------------------
#define PREP_TOT 1576064
__global__ __launch_bounds__(256) void kprep_conv(
    const void* x, const void* Wq, const void* bq, const void* Wk, const void* bk,
    const void* Wv, const void* bv, const void* Wo, const void* bo,
    const int* __restrict__ flags,
    u16* xb, u16* Wqb, u16* Wkb, u16* Wvb, u16* Wob,
    u16* bqb, u16* bkb, u16* bvb, u16* bob) {
    int gid = blockIdx.x * 256 + threadIdx.x;
    if (gid >= PREP_TOT) return;
    const int dt = flags[0];
    const void* src; u16* dst; int off;
    if      (gid < 1048576) { src = x;  dst = xb;  off = gid; }
    else if (gid < 1179648) { src = Wq; dst = Wqb; off = gid - 1048576; }
    else if (gid < 1310720) { src = Wk; dst = Wkb; off = gid - 1179648; }
    else if (gid < 1441792) { src = Wv; dst = Wvb; off = gid - 1310720; }
    else if (gid < 1572864) { src = Wo; dst = Wob; off = gid - 1441792; }
    else if (gid < 1573888) { src = bq; dst = bqb; off = gid - 1572864; }
    else if (gid < 1574912) { src = bk; dst = bkb; off = gid - 1573888; }
    else if (gid < 1575936) { src = bv; dst = bvb; off = gid - 1574912; }
    else                    { src = bo; dst = bob; off = gid - 1575936; }
    dst[off] = dt ? ((const u16*)src)[off] : f2bf(((const float*)src)[off]);
}

// ---------------------------------------------------------------
// Kprep_mask: pack pad_mask into bitmask [16][512][16 u32 words],
// and zero the column-sum accumulator lsum[128*512].
// ---------------------------------------------------------------
__global__ __launch_bounds__(256) void kprep_mask(const void* __restrict__ pad,
                                                  const int* __restrict__ flags,
                                                  unsigned* __restrict__ mb,
                                                  float* __restrict__ lsum) {
    int w = blockIdx.x * 256 + threadIdx.x;     // < 131072
    if (w < 65536) lsum[w] = 0.f;
    size_t base = (size_t)w * 32;
    unsigned m = 0;
    if (flags[1]) {
        const unsigned char* p = (const unsigned char*)pad;
#pragma unroll
        for (int b = 0; b < 32; b++) m |= (p[base + b] ? 1u : 0u) << b;
    } else {
        const int* p = (const int*)pad;
#pragma unroll
        for (int b = 0; b < 32; b++) m |= (p[base + b] ? 1u : 0u) << b;
    }
    mb[w] = m;
}

// ---------------------------------------------------------------
// K1: QKV projection via MFMA.  y = x @ W^T + b.
// q,k head-major [n][l][d]; v TRANSPOSED [n][d][l] (unscaled).
// grid (128 m-tiles, 8 heads, 3 z) — m fastest so the 24 blocks sharing
// an x-tile land on one XCD.  128 threads (2 waves).
// ---------------------------------------------------------------
__global__ __launch_bounds__(128) void k1_proj(
    const u16* __restrict__ xb,
    const u16* __restrict__ Wqb, const u16* __restrict__ Wkb, const u16* __restrict__ Wvb,
    const u16* __restrict__ bqb, const u16* __restrict__ bkb, const u16* __restrict__ bvb,
    u16* __restrict__ qb, u16* __restrict__ kb, u16* __restrict__ vtb) {
    const int m0 = blockIdx.x * 64;
    const int h  = blockIdx.y;
    const int z  = blockIdx.z;
    const u16* W    = (z == 0) ? Wqb : (z == 1) ? Wkb : Wvb;
    const u16* bias = (z == 0) ? bqb : (z == 1) ? bkb : bvb;

    const int lane = threadIdx.x & 63, wc = threadIdx.x >> 6;
    const int mr = lane & 15, quad = lane >> 4;

    f32x4 acc[4][4];
#pragma unroll
    for (int i = 0; i < 4; i++)
#pragma unroll
        for (int j = 0; j < 4; j++) acc[i][j] = (f32x4){0.f, 0.f, 0.f, 0.f};

    mfma_bt64(xb + (size_t)m0 * D_, D_,
              W + (size_t)(h * 128 + wc * 64) * D_, D_, D_, lane, acc);

    __shared__ __align__(16) u16 T[64][136];
#pragma unroll
    for (int i = 0; i < 4; i++)
#pragma unroll
        for (int j = 0; j < 4; j++) {
            int col = wc * 64 + j * 16 + mr;
            float bv_ = bf2f(bias[h * 128 + col]);
#pragma unroll
            for (int r = 0; r < 4; r++)
                T[i * 16 + quad * 4 + r][col] = f2bf(acc[i][j][r] + bv_);
        }
    __syncthreads();

    const int bb = m0 >> 9, l0 = m0 & 511;
    const int t = threadIdx.x;
    if (z < 2) {
        u16* out = z ? kb : qb;
        int row = t >> 1, c0 = (t & 1) * 64;
        u16* dst = out + ((size_t)(h * B_ + bb) * L_ + l0 + row) * D_ + c0;
#pragma unroll
        for (int c = 0; c < 64; c += 8)
            *(uint4*)(dst + c) = *(const uint4*)&T[row][c0 + c];
    } else {
        // thread t owns d-column t: gather 64 l's, 128 B contiguous store
        u16* dst = vtb + ((size_t)(h * B_ + bb) * D_ + t) * L_ + l0;
#pragma unroll
        for (int c = 0; c < 64; c += 8) {
            u16 tmp[8];
#pragma unroll
            for (int s = 0; s < 8; s++) tmp[s] = T[c + s][t];
            *(uint4*)(dst + c) = *(const uint4*)tmp;
        }
    }
}

// ---------------------------------------------------------------
// K2a: partial column sums of exp(masked qk*rs), atomically added into
// lsum[n][k].  grid (128 n, 4 k-strips, 2 q-halves), 256 threads.
// Exactly 2 commutative fp32 addends per address => deterministic.
// ---------------------------------------------------------------
__global__ __launch_bounds__(256) void k2a_lsum(
    const u16* __restrict__ qb, const u16* __restrict__ kb,
    const unsigned* __restrict__ mbits, float* __restrict__ lsum) {
    const int n     = blockIdx.x;
    const int ks    = blockIdx.y * 128;
    const int qbase = blockIdx.z * 256;
    const int bb    = n & (B_ - 1);
    const int tid = threadIdx.x;
    const int lane = tid & 63, wave = tid >> 6;
    const int wr = wave >> 1, wc = wave & 1;
    const int mr = lane & 15, quad = lane >> 4;
    const float rs = 0.08838834764831845f;   // 1/sqrt(128)

    __shared__ unsigned mw[1024];            // [q 256][4 words of this strip]
    __shared__ float CS[2][128];
#pragma unroll
    for (int s = 0; s < 4; s++) {
        int idx = tid * 4 + s;
        int q = idx >> 2, lw = idx & 3;
        mw[idx] = mbits[((size_t)(bb << 9) + qbase + q) * 16 + blockIdx.y * 4 + lw];
    }
    __syncthreads();

    const u16* qn = qb + (size_t)n * L_ * D_;
    const u16* kB = kb + (size_t)n * L_ * D_ + (size_t)(ks + wc * 64) * D_;

    float colsum[4] = {0.f, 0.f, 0.f, 0.f};
    for (int qt = 0; qt < 2; qt++) {
        const int ql0 = wr * 128 + qt * 64;   // local q within the 256
        f32x4 acc[4][4];
#pragma unroll
        for (int i = 0; i < 4; i++)
#pragma unroll
            for (int j = 0; j < 4; j++) acc[i][j] = (f32x4){0.f, 0.f, 0.f, 0.f};
        mfma_bt64(qn + (size_t)(qbase + ql0) * D_, D_, kB, D_, D_, lane, acc);
#pragma unroll
        for (int j = 0; j < 4; j++) {
            const int lw = wc * 2 + (j >> 1);
            const int bit = (j & 1) * 16 + mr;
#pragma unroll
            for (int i = 0; i < 4; i++)
#pragma unroll
                for (int r = 0; r < 4; r++) {
                    int ql = ql0 + i * 16 + quad * 4 + r;
                    if (!((mw[(ql << 2) + lw] >> bit) & 1u))
                        colsum[j] += __expf(acc[i][j][r] * rs);
                }
        }
    }
#pragma unroll
    for (int j = 0; j < 4; j++) {
        colsum[j] += __shfl_xor(colsum[j], 16);
        colsum[j] += __shfl_xor(colsum[j], 32);
    }
    if (quad == 0) {
#pragma unroll
        for (int j = 0; j < 4; j++) CS[wr][wc * 64 + j * 16 + mr] = colsum[j];
    }
    __syncthreads();
    if (tid < 128)
        atomicAdd(&lsum[(size_t)n * L_ + ks + tid], CS[0][tid] + CS[1][tid]);
}

// ---------------------------------------------------------------
// K2b: fused attention, 64-q blocks.  grid (128 n, 8 q-tiles), 256 thr.
// Per 256-k chunk: 4 waves compute disjoint 64x64 QK tiles -> eS,
// then PV with per-wave 64x32 output slices (no reduction phase).
// ---------------------------------------------------------------
__global__ __launch_bounds__(256) void k2b_attn(
    const u16* __restrict__ qb, const u16* __restrict__ kb,
    const u16* __restrict__ vtb, const unsigned* __restrict__ mbits,
    const float* __restrict__ lsum, u16* __restrict__ att) {
    const int n  = blockIdx.x;
    const int q0 = blockIdx.y * 64;
    const int bb = n & (B_ - 1);
    const int tid = threadIdx.x;
    const int lane = tid & 63, w = tid >> 6;
    const int mr = lane & 15, quad = lane >> 4;
    const float rs = 0.08838834764831845f;

    __shared__ __align__(16) u16 eS[64 * 264];   // 64 x 256 (+8 pad), 33.8 KB
    __shared__ unsigned mwq[1024];               // [q 64][16 words]
    __shared__ float linvS[512];

#pragma unroll
    for (int s = 0; s < 4; s++) {
        int idx = tid * 4 + s;
        int ql = idx >> 4, wd = idx & 15;
        mwq[idx] = mbits[((size_t)(bb << 9) + q0 + ql) * 16 + wd];
    }
    if (tid < 128) {
        float4 ls = *(const float4*)&lsum[(size_t)n * L_ + tid * 4];
        linvS[tid * 4 + 0] = 1.f / ls.x;
        linvS[tid * 4 + 1] = 1.f / ls.y;
        linvS[tid * 4 + 2] = 1.f / ls.z;
        linvS[tid * 4 + 3] = 1.f / ls.w;
    }
    __syncthreads();

    const u16* qn = qb + (size_t)n * L_ * D_ + (size_t)q0 * D_;
    const u16* kn = kb + (size_t)n * L_ * D_;
    const u16* vn = vtb + (size_t)n * D_ * L_;

    f32x4 accd[4][2];
#pragma unroll
    for (int i = 0; i < 4; i++)
#pragma unroll
        for (int j = 0; j < 2; j++) accd[i][j] = (f32x4){0.f, 0.f, 0.f, 0.f};

    for (int it = 0; it < 2; it++) {
        const int kc0 = it * 256 + w * 64;       // this wave's 64 score cols
        f32x4 qk[4][4];
#pragma unroll
        for (int i = 0; i < 4; i++)
#pragma unroll
            for (int j = 0; j < 4; j++) qk[i][j] = (f32x4){0.f, 0.f, 0.f, 0.f};
        mfma_bt64(qn, D_, kn + (size_t)kc0 * D_, D_, D_, lane, qk);

#pragma unroll
        for (int j = 0; j < 4; j++) {
            const int kc = kc0 + j * 16 + mr;
            const int wd = kc >> 5;
            const int bit = kc & 31;
            const float lv = linvS[kc];
            const int colL = w * 64 + j * 16 + mr;
#pragma unroll
            for (int i = 0; i < 4; i++)
#pragma unroll
                for (int r = 0; r < 4; r++) {
                    int ql = i * 16 + quad * 4 + r;
                    float e = ((mwq[(ql << 4) + wd] >> bit) & 1u)
                              ? 0.f : __expf(qk[i][j][r] * rs) * lv;
                    eS[ql * 264 + colL] = f2bf(e);
                }
        }
        __syncthreads();

        // PV: wave w owns d-cols w*32..w*32+32, full 256-k chunk
#pragma unroll
        for (int kk = 0; kk < 8; kk++) {
            s16x8 av[4], bv[2];
#pragma unroll
            for (int i = 0; i < 4; i++)
                av[i] = *(const s16x8*)&eS[(i * 16 + mr) * 264 + kk * 32 + quad * 8];
#pragma unroll
            for (int j = 0; j < 2; j++)
                bv[j] = *(const s16x8*)(vn + (size_t)(w * 32 + j * 16 + mr) * L_
                                        + it * 256 + kk * 32 + quad * 8);
#pragma unroll
            for (int i = 0; i < 4; i++)
#pragma unroll
                for (int j = 0; j < 2; j++)
                    accd[i][j] = __builtin_amdgcn_mfma_f32_16x16x32_bf16(av[i], bv[j], accd[i][j], 0, 0, 0);
        }
        __syncthreads();
    }

    // epilogue: reuse eS as [64][136] bf16 out-tile, coalesced store
#pragma unroll
    for (int i = 0; i < 4; i++)
#pragma unroll
        for (int j = 0; j < 2; j++) {
            int col = w * 32 + j * 16 + mr;
#pragma unroll
            for (int r = 0; r < 4; r++)
                eS[(i * 16 + quad * 4 + r) * 136 + col] = f2bf(accd[i][j][r]);
        }
    __syncthreads();
    int row = tid >> 2, c0 = (tid & 3) * 32;
    u16* dst = att + ((size_t)n * L_ + q0 + row) * D_ + c0;
#pragma unroll
    for (int c = 0; c < 32; c += 8)
        *(uint4*)(dst + c) = *(const uint4*)&eS[row * 136 + c0 + c];
}

// ---------------------------------------------------------------
// K5: out = att_flat[8192][1024] @ Wo[128][1024]^T + bo.
// grid (2 n-halves, 128 m-tiles), 128 threads (2 waves splitting K),
// LDS fp32 reduction.  dt-switched output.
// ---------------------------------------------------------------
__global__ __launch_bounds__(128) void k5_out(
    const u16* __restrict__ att, const u16* __restrict__ Wob,
    const u16* __restrict__ bob, const int* __restrict__ flags,
    void* __restrict__ out) {
    const int dt = flags[0];
    const int n0 = blockIdx.x * 64;
    const int m0 = blockIdx.y * 64;
    const int lane = threadIdx.x & 63, wk = threadIdx.x >> 6;
    const int mr = lane & 15, quad = lane >> 4;

    f32x4 acc[4][4];
#pragma unroll
    for (int i = 0; i < 4; i++)
#pragma unroll
        for (int j = 0; j < 4; j++) acc[i][j] = (f32x4){0.f, 0.f, 0.f, 0.f};

    mfma_bt64(att + (size_t)m0 * HD_ + wk * 512, HD_,
              Wob + (size_t)n0 * HD_ + wk * 512, HD_, 512, lane, acc);

    __shared__ __align__(16) float Tf[64][68];
    if (wk == 0) {
#pragma unroll
        for (int i = 0; i < 4; i++)
#pragma unroll
            for (int j = 0; j < 4; j++)
#pragma unroll
                for (int r = 0; r < 4; r++)
                    Tf[i * 16 + quad * 4 + r][j * 16 + mr] = acc[i][j][r];
    }
    __syncthreads();
    if (wk == 1) {
#pragma unroll
        for (int i = 0; i < 4; i++)
#pragma unroll
            for (int j = 0; j < 4; j++)
#pragma unroll
                for (int r = 0; r < 4; r++)
                    Tf[i * 16 + quad * 4 + r][j * 16 + mr] += acc[i][j][r];
    }
    __syncthreads();

    int t = threadIdx.x, row = t >> 1, h0 = (t & 1) * 32;
    size_t base = (size_t)(m0 + row) * D_ + n0 + h0;
    if (dt) {
        u16* o = (u16*)out;
#pragma unroll
        for (int c = 0; c < 32; c += 8) {
            u16 tmp[8];
#pragma unroll
            for (int s = 0; s < 8; s++)
                tmp[s] = f2bf(Tf[row][h0 + c + s] + bf2f(bob[n0 + h0 + c + s]));
            *(uint4*)(o + base + c) = *(const uint4*)tmp;
        }
    } else {
        float* o = (float*)out;
#pragma unroll
        for (int c = 0; c < 32; c += 4) {
            float4 v;
            v.x = Tf[row][h0 + c + 0] + bf2f(bob[n0 + h0 + c + 0]);
            v.y = Tf[row][h0 + c + 1] + bf2f(bob[n0 + h0 + c + 1]);
            v.z = Tf[row][h0 + c + 2] + bf2f(bob[n0 + h0 + c + 2]);
            v.w = Tf[row][h0 + c + 3] + bf2f(bob[n0 + h0 + c + 3]);
            *(float4*)(o + base + c) = v;
        }
    }
}

// ---------------------------------------------------------------
extern "C" void kernel_launch(void* const* d_in, const int* in_sizes, int n_in,
                              void* d_out, int out_size, void* d_ws, size_t ws_size,
                              hipStream_t stream) {
    (void)in_sizes; (void)n_in; (void)out_size; (void)ws_size;
    const void* x  = d_in[0];
    const void* Wq = d_in[1]; const void* bq = d_in[2];
    const void* Wk = d_in[3]; const void* bk = d_in[4];
    const void* Wv = d_in[5]; const void* bv = d_in[6];
    const void* Wo = d_in[7]; const void* bo = d_in[8];
    const void* pad = d_in[9];

    char* p = (char*)d_ws;
    auto alloc = [&](size_t bytes) { char* r = p; p += (bytes + 255) & ~(size_t)255; return r; };
    int*  flags = (int*)alloc(256);
    u16*  xb   = (u16*)alloc(2097152);
    u16*  Wqb  = (u16*)alloc(262144);
    u16*  Wkb  = (u16*)alloc(262144);
    u16*  Wvb  = (u16*)alloc(262144);
    u16*  Wob  = (u16*)alloc(262144);
    u16*  bqb  = (u16*)alloc(2048);
    u16*  bkb  = (u16*)alloc(2048);
    u16*  bvb  = (u16*)alloc(2048);
    u16*  bob  = (u16*)alloc(256);
    unsigned* mbits = (unsigned*)alloc(524288);
    float* lsum = (float*)alloc(262144);
    u16*  qb   = (u16*)alloc(16777216);
    u16*  kb   = (u16*)alloc(16777216);
    u16*  vtb  = (u16*)alloc(16777216);
    u16*  att  = (u16*)alloc(16777216);

    k0_detect<<<1, 256, 0, stream>>>((const unsigned*)pad, (const unsigned*)x, flags);
    kprep_conv<<<(PREP_TOT + 255) / 256, 256, 0, stream>>>(
        x, Wq, bq, Wk, bk, Wv, bv, Wo, bo, flags,
        xb, Wqb, Wkb, Wvb, Wob, bqb, bkb, bvb, bob);
    kprep_mask<<<512, 256, 0, stream>>>(pad, flags, mbits, lsum);
    k1_proj<<<dim3(128, 8, 3), 128, 0, stream>>>(
        xb, Wqb, Wkb, Wvb, bqb, bkb, bvb, qb, kb, vtb);
    k2a_lsum<<<dim3(128, 4, 2), 256, 0, stream>>>(qb, kb, mbits, lsum);
    k2b_attn<<<dim3(128, 8), 256, 0, stream>>>(qb, kb, vtb, mbits, lsum, att);
    k5_out<<<dim3(2, 128), 128, 0, stream>>>(att, Wob, bob, flags, d_out);
}

// Round 6
// 263.263 us; speedup vs baseline: 1.0303x; 1.0303x over previous
//
#include <hip/hip_runtime.h>

// Problem constants (B, L, D, H) = (16, 512, 128, 8)
#define B_  16
#define L_  512
#define D_  128
#define H_  8
#define HD_ 1024   // H*D
#define NH_ 128    // H*B
#define M_  8192   // B*L

typedef unsigned short u16;
typedef __attribute__((ext_vector_type(8))) short s16x8;   // 8 bf16 = 4 VGPRs
typedef __attribute__((ext_vector_type(4))) float f32x4;   // MFMA accumulator

// ---------- bf16 helpers ----------
__device__ __forceinline__ float bf2f(u16 u) {
    union { unsigned u; float f; } x; x.u = ((unsigned)u) << 16; return x.f;
}
__device__ __forceinline__ u16 f2bf(float f) {
    unsigned u = __float_as_uint(f);
    return (u16)((u + 0x7FFFu + ((u >> 16) & 1u)) >> 16);   // RNE
}

// ---------------------------------------------------------------
// MFMA bt-core: C(MI*16 x MJ*16) = A @ B^T for one wave.
// A/B operand: row = lane&15, k = (lane>>4)*8 + j  (16B contiguous)
// C/D: col = lane&15, row = (lane>>4)*4 + reg   (m89/m91-verified)
// ---------------------------------------------------------------
template<int MI, int MJ>
__device__ __forceinline__ void mfma_bt(const u16* __restrict__ A, int lda,
                                        const u16* __restrict__ B, int ldb,
                                        int K, int lane, f32x4 acc[MI][MJ]) {
    const int mr = lane & 15, quad = lane >> 4;
    for (int k0 = 0; k0 < K; k0 += 32) {
        s16x8 av[MI], bv[MJ];
#pragma unroll
        for (int i = 0; i < MI; i++)
            av[i] = *(const s16x8*)(A + (size_t)(i * 16 + mr) * lda + k0 + quad * 8);
#pragma unroll
        for (int j = 0; j < MJ; j++)
            bv[j] = *(const s16x8*)(B + (size_t)(j * 16 + mr) * ldb + k0 + quad * 8);
#pragma unroll
        for (int i = 0; i < MI; i++)
#pragma unroll
            for (int j = 0; j < MJ; j++)
                acc[i][j] = __builtin_amdgcn_mfma_f32_16x16x32_bf16(av[i], bv[j], acc[i][j], 0, 0, 0);
    }
}

// ---------------------------------------------------------------
// K0: detect float dtype (fp32 vs packed bf16) + mask dtype (i32 vs u8).
// ---------------------------------------------------------------
__global__ void k0_detect(const unsigned int* __restrict__ pad,
                          const unsigned int* __restrict__ xw,
                          int* __restrict__ flags) {
    __shared__ int sMask, sCnt;
    if (threadIdx.x == 0) { sMask = 0; sCnt = 0; }
    __syncthreads();
    int bad = 0;
#pragma unroll
    for (int i = 0; i < 4; i++) {
        unsigned u = pad[threadIdx.x * 4 + i];
        bad |= (u > 1u) ? 1 : 0;
    }
    int cnt = 0;
#pragma unroll
    for (int i = 0; i < 16; i++) {
        unsigned w = xw[threadIdx.x * 16 + i];
        unsigned e = (w >> 7) & 0xFFu;
        cnt += (e >= 100u && e <= 131u) ? 1 : 0;
    }
    if (bad) atomicOr(&sMask, 1);
    atomicAdd(&sCnt, cnt);
    __syncthreads();
    if (threadIdx.x == 0) {
        flags[0] = (sCnt > 2048) ? 1 : 0;   // 1 => floats are bf16
        flags[1] = sMask;                   // 1 => mask is uint8
    }
}

// ---------------------------------------------------------------
// Kprep_conv8: normalize float inputs to bf16, 8 elems/thread.
// Segment boundaries are all multiples of 8.
// ---------------------------------------------------------------
#define PREP_G8 197008   // 1576064 / 8
__global__ __launch_bounds__(256) void kprep_conv8(
    const void* x, const void* Wq, const void* bq, const void* Wk, const void* bk,
    const void* Wv, const void* bv, const void* Wo, const void* bo,
    const int* __restrict__ flags,
    u16* xb, u16* Wqb, u16* Wkb, u16* Wvb, u16* Wob,
    u16* bqb, u16* bkb, u16* bvb, u16* bob) {
    int g = blockIdx.x * 256 + threadIdx.x;
    if (g >= PREP_G8) return;
    int e0 = g * 8;
    const int dt = flags[0];
    const void* src; u16* dst; int off;
    if      (e0 < 1048576) { src = x;  dst = xb;  off = e0; }
    else if (e0 < 1179648) { src = Wq; dst = Wqb; off = e0 - 1048576; }
    else if (e0 < 1310720) { src = Wk; dst = Wkb; off = e0 - 1179648; }
    else if (e0 < 1441792) { src = Wv; dst = Wvb; off = e0 - 1310720; }
    else if (e0 < 1572864) { src = Wo; dst = Wob; off = e0 - 1441792; }
    else if (e0 < 1573888) { src = bq; dst = bqb; off = e0 - 1572864; }
    else if (e0 < 1574912) { src = bk; dst = bkb; off = e0 - 1573888; }
    else if (e0 < 1575936) { src = bv; dst = bvb; off = e0 - 1574912; }
    else                   { src = bo; dst = bob; off = e0 - 1575936; }
    if (dt) {
        *(uint4*)(dst + off) = *(const uint4*)((const u16*)src + off);
    } else {
        float4 a = *(const float4*)((const float*)src + off);
        float4 b = *(const float4*)((const float*)src + off + 4);
        u16 t[8] = {f2bf(a.x), f2bf(a.y), f2bf(a.z), f2bf(a.w),
                    f2bf(b.x), f2bf(b.y), f2bf(b.z), f2bf(b.w)};
        *(uint4*)(dst + off) = *(const uint4*)t;
    }
}

// ---------------------------------------------------------------
// Kprep_mask: pack pad_mask into bitmask [16][512][16 u32 words],
// vectorized loads; also zero lsum[128*512].
// ---------------------------------------------------------------
__global__ __launch_bounds__(256) void kprep_mask(const void* __restrict__ pad,
                                                  const int* __restrict__ flags,
                                                  unsigned* __restrict__ mb,
                                                  float* __restrict__ lsum) {
    int w = blockIdx.x * 256 + threadIdx.x;     // < 131072
    if (w < 65536) lsum[w] = 0.f;
    unsigned m = 0;
    if (flags[1]) {
        union { uint4 v[2]; unsigned a[8]; } u;
        u.v[0] = ((const uint4*)pad)[w * 2];
        u.v[1] = ((const uint4*)pad)[w * 2 + 1];
#pragma unroll
        for (int b = 0; b < 32; b++)
            m |= (((u.a[b >> 2] >> ((b & 3) * 8)) & 0xFFu) ? 1u : 0u) << b;
    } else {
        union { uint4 v[8]; unsigned a[32]; } u;
#pragma unroll
        for (int i = 0; i < 8; i++) u.v[i] = ((const uint4*)pad)[w * 8 + i];
#pragma unroll
        for (int b = 0; b < 32; b++) m |= (u.a[b] ? 1u : 0u) << b;
    }
    mb[w] = m;
}

// ---------------------------------------------------------------
// K1: QKV projection via MFMA.  y = x @ W^T + b.
// q,k head-major [n][l][d]; v TRANSPOSED [n][d][l] (unscaled).
// grid (8 heads, 64 m-tiles, 3), 256 threads.
// ---------------------------------------------------------------
__global__ __launch_bounds__(256) void k1_proj(
    const u16* __restrict__ xb,
    const u16* __restrict__ Wqb, const u16* __restrict__ Wkb, const u16* __restrict__ Wvb,
    const u16* __restrict__ bqb, const u16* __restrict__ bkb, const u16* __restrict__ bvb,
    u16* __restrict__ qb, u16* __restrict__ kb, u16* __restrict__ vtb) {
    const int h  = blockIdx.x;
    const int m0 = blockIdx.y * 128;
    const int z  = blockIdx.z;
    const u16* W    = (z == 0) ? Wqb : (z == 1) ? Wkb : Wvb;
    const u16* bias = (z == 0) ? bqb : (z == 1) ? bkb : bvb;

    const int lane = threadIdx.x & 63, wave = threadIdx.x >> 6;
    const int wr = wave >> 1, wc = wave & 1;
    const int mr = lane & 15, quad = lane >> 4;

    f32x4 acc[4][4];
#pragma unroll
    for (int i = 0; i < 4; i++)
#pragma unroll
        for (int j = 0; j < 4; j++) acc[i][j] = (f32x4){0.f, 0.f, 0.f, 0.f};

    mfma_bt<4,4>(xb + (size_t)(m0 + wr * 64) * D_, D_,
                 W + (size_t)(h * 128 + wc * 64) * D_, D_, D_, lane, acc);

    __shared__ __align__(16) u16 T[128][136];
#pragma unroll
    for (int i = 0; i < 4; i++)
#pragma unroll
        for (int j = 0; j < 4; j++) {
            int col = wc * 64 + j * 16 + mr;
            float bv_ = bf2f(bias[h * 128 + col]);
#pragma unroll
            for (int r = 0; r < 4; r++)
                T[wr * 64 + i * 16 + quad * 4 + r][col] = f2bf(acc[i][j][r] + bv_);
        }
    __syncthreads();

    const int bb = m0 >> 9, l0 = m0 & 511;
    const int t = threadIdx.x;
    if (z < 2) {
        u16* out = z ? kb : qb;
        int row = t >> 1, c0 = (t & 1) * 64;
        u16* dst = out + ((size_t)(h * B_ + bb) * L_ + l0 + row) * D_ + c0;
#pragma unroll
        for (int c = 0; c < 64; c += 8)
            *(uint4*)(dst + c) = *(const uint4*)&T[row][c0 + c];
    } else {
        int d = t >> 1, lc0 = (t & 1) * 64;
        u16* dst = vtb + ((size_t)(h * B_ + bb) * D_ + d) * L_ + l0 + lc0;
#pragma unroll
        for (int c = 0; c < 64; c += 8) {
            u16 tmp[8];
#pragma unroll
            for (int s = 0; s < 8; s++) tmp[s] = T[lc0 + c + s][d];
            *(uint4*)(dst + c) = *(const uint4*)tmp;
        }
    }
}

// ---------------------------------------------------------------
// K2: E[n,q,k] = exp((mask? -1e9 : q.k) * rs) materialized bf16,
// plus column-sum partials atomically added to lsum[n,k].
// grid (128 n, 4 ks, 4 qq), 256 threads, 2 barriers.
// ---------------------------------------------------------------
__global__ __launch_bounds__(256) void k2_escore(
    const u16* __restrict__ qb, const u16* __restrict__ kb,
    const unsigned* __restrict__ mbits,
    u16* __restrict__ E, float* __restrict__ lsum) {
    const int n  = blockIdx.x;
    const int ks = blockIdx.y;       // k-strip of 128
    const int qq = blockIdx.z;       // q-strip of 128
    const int bb = n & (B_ - 1);
    const int tid = threadIdx.x;
    const int lane = tid & 63, wave = tid >> 6;
    const int wr = wave >> 1, wc = wave & 1;
    const int mr = lane & 15, quad = lane >> 4;
    const float rs = 0.08838834764831845f;   // 1/sqrt(128)

    __shared__ __align__(16) u16 Te[128][136];
    __shared__ unsigned mw[512];             // [q 128][4 words of strip]
    __shared__ float CS[2][128];

#pragma unroll
    for (int s = 0; s < 2; s++) {
        int idx = tid * 2 + s;
        int ql = idx >> 2, lw = idx & 3;
        mw[idx] = mbits[((size_t)(bb << 9) + qq * 128 + ql) * 16 + ks * 4 + lw];
    }
    __syncthreads();

    f32x4 acc[4][4];
#pragma unroll
    for (int i = 0; i < 4; i++)
#pragma unroll
        for (int j = 0; j < 4; j++) acc[i][j] = (f32x4){0.f, 0.f, 0.f, 0.f};

    mfma_bt<4,4>(qb + (size_t)n * L_ * D_ + (size_t)(qq * 128 + wr * 64) * D_, D_,
                 kb + (size_t)n * L_ * D_ + (size_t)(ks * 128 + wc * 64) * D_, D_,
                 D_, lane, acc);

    float colsum[4] = {0.f, 0.f, 0.f, 0.f};
#pragma unroll
    for (int j = 0; j < 4; j++) {
        const int kc = wc * 64 + j * 16 + mr;
        const int lw = kc >> 5, bit = kc & 31;
#pragma unroll
        for (int i = 0; i < 4; i++)
#pragma unroll
            for (int r = 0; r < 4; r++) {
                int ql = wr * 64 + i * 16 + quad * 4 + r;
                float e = ((mw[(ql << 2) + lw] >> bit) & 1u)
                          ? 0.f : __expf(acc[i][j][r] * rs);
                colsum[j] += e;
                Te[ql][kc] = f2bf(e);
            }
    }
#pragma unroll
    for (int j = 0; j < 4; j++) {
        colsum[j] += __shfl_xor(colsum[j], 16);
        colsum[j] += __shfl_xor(colsum[j], 32);
    }
    if (quad == 0) {
#pragma unroll
        for (int j = 0; j < 4; j++) CS[wr][wc * 64 + j * 16 + mr] = colsum[j];
    }
    __syncthreads();

    {
        int row = tid >> 1, c0 = (tid & 1) * 64;
        u16* dst = E + ((size_t)(n * L_ + qq * 128 + row)) * L_ + ks * 128 + c0;
#pragma unroll
        for (int c = 0; c < 64; c += 8)
            *(uint4*)(dst + c) = *(const uint4*)&Te[row][c0 + c];
    }
    if (tid < 128)
        atomicAdd(&lsum[(size_t)n * L_ + ks * 128 + tid], CS[0][tid] + CS[1][tid]);
}

// ---------------------------------------------------------------
// K3: fold softmax normalization into V^T:  vt[n][d][k] /= lsum[n][k].
// 8 elements/thread, grid 4096 x 256.
// ---------------------------------------------------------------
__global__ __launch_bounds__(256) void k3_vscale(u16* __restrict__ vtb,
                                                 const float* __restrict__ lsum) {
    int idx = blockIdx.x * 256 + threadIdx.x;      // < 1048576
    int n = idx >> 13;
    int rem = idx & 8191;
    int d = rem >> 6;
    int kg = (rem & 63) << 3;
    u16* p = vtb + ((size_t)n * D_ + d) * L_ + kg;
    uint4 v = *(const uint4*)p;
    float4 l0 = *(const float4*)(lsum + (size_t)n * L_ + kg);
    float4 l1 = *(const float4*)(lsum + (size_t)n * L_ + kg + 4);
    float lv[8] = {1.f/l0.x, 1.f/l0.y, 1.f/l0.z, 1.f/l0.w,
                   1.f/l1.x, 1.f/l1.y, 1.f/l1.z, 1.f/l1.w};
    u16* u = (u16*)&v;
#pragma unroll
    for (int s = 0; s < 8; s++) u[s] = f2bf(bf2f(u[s]) * lv[s]);
    *(uint4*)p = v;
}

// ---------------------------------------------------------------
// K4: att[n,q,d] = E[n] @ V'^T[n].  grid (128 n, 8 q-tiles), 256 thr.
// Wave w computes 64q x 32d slice over full K=512.
// ---------------------------------------------------------------
__global__ __launch_bounds__(256) void k4_av(
    const u16* __restrict__ E, const u16* __restrict__ vtb,
    u16* __restrict__ att) {
    const int n  = blockIdx.x;
    const int qt = blockIdx.y;
    const int tid = threadIdx.x;
    const int lane = tid & 63, w = tid >> 6;
    const int mr = lane & 15, quad = lane >> 4;

    f32x4 acc[4][2];
#pragma unroll
    for (int i = 0; i < 4; i++)
#pragma unroll
        for (int j = 0; j < 2; j++) acc[i][j] = (f32x4){0.f, 0.f, 0.f, 0.f};

    mfma_bt<4,2>(E + ((size_t)n * L_ + qt * 64) * L_, L_,
                 vtb + ((size_t)n * D_ + w * 32) * L_, L_, L_, lane, acc);

    __shared__ __align__(16) u16 Ta[64][136];
#pragma unroll
    for (int i = 0; i < 4; i++)
#pragma unroll
        for (int j = 0; j < 2; j++) {
            int col = w * 32 + j * 16 + mr;
#pragma unroll
            for (int r = 0; r < 4; r++)
                Ta[i * 16 + quad * 4 + r][col] = f2bf(acc[i][j][r]);
        }
    __syncthreads();
    int row = tid >> 2, c0 = (tid & 3) * 32;
    u16* dst = att + ((size_t)(n * L_ + qt * 64 + row)) * D_ + c0;
#pragma unroll
    for (int c = 0; c < 32; c += 8)
        *(uint4*)(dst + c) = *(const uint4*)&Ta[row][c0 + c];
}

// ---------------------------------------------------------------
// K5: out = att_flat[8192][1024] @ Wo[128][1024]^T + bo.
// grid (2 n-halves, 256 m-tiles of 32), 256 thr: 4 waves split K=1024
// into 256 each, LDS fp32 reduction.  dt-switched output.
// ---------------------------------------------------------------
__global__ __launch_bounds__(256) void k5_out(
    const u16* __restrict__ att, const u16* __restrict__ Wob,
    const u16* __restrict__ bob, const int* __restrict__ flags,
    void* __restrict__ out) {
    const int dt = flags[0];
    const int n0 = blockIdx.x * 64;
    const int m0 = blockIdx.y * 32;
    const int tid = threadIdx.x;
    const int lane = tid & 63, wk = tid >> 6;
    const int mr = lane & 15, quad = lane >> 4;

    f32x4 acc[2][4];
#pragma unroll
    for (int i = 0; i < 2; i++)
#pragma unroll
        for (int j = 0; j < 4; j++) acc[i][j] = (f32x4){0.f, 0.f, 0.f, 0.f};

    mfma_bt<2,4>(att + (size_t)m0 * HD_ + wk * 256, HD_,
                 Wob + (size_t)n0 * HD_ + wk * 256, HD_, 256, lane, acc);

    __shared__ __align__(16) float Tf[2][32][68];
    if (wk < 2) {
#pragma unroll
        for (int i = 0; i < 2; i++)
#pragma unroll
            for (int j = 0; j < 4; j++)
#pragma unroll
                for (int r = 0; r < 4; r++)
                    Tf[wk][i * 16 + quad * 4 + r][j * 16 + mr] = acc[i][j][r];
    }
    __syncthreads();
    if (wk >= 2) {
#pragma unroll
        for (int i = 0; i < 2; i++)
#pragma unroll
            for (int j = 0; j < 4; j++)
#pragma unroll
                for (int r = 0; r < 4; r++)
                    Tf[wk - 2][i * 16 + quad * 4 + r][j * 16 + mr] += acc[i][j][r];
    }
    __syncthreads();

    int row = tid >> 3, c0 = (tid & 7) * 8;
    size_t base = (size_t)(m0 + row) * D_ + n0 + c0;
    float v[8];
#pragma unroll
    for (int s = 0; s < 8; s++)
        v[s] = Tf[0][row][c0 + s] + Tf[1][row][c0 + s] + bf2f(bob[n0 + c0 + s]);
    if (dt) {
        u16 tmp[8];
#pragma unroll
        for (int s = 0; s < 8; s++) tmp[s] = f2bf(v[s]);
        *(uint4*)((u16*)out + base) = *(const uint4*)tmp;
    } else {
        float* o = (float*)out;
        *(float4*)(o + base)     = *(const float4*)&v[0];
        *(float4*)(o + base + 4) = *(const float4*)&v[4];
    }
}

// ---------------------------------------------------------------
extern "C" void kernel_launch(void* const* d_in, const int* in_sizes, int n_in,
                              void* d_out, int out_size, void* d_ws, size_t ws_size,
                              hipStream_t stream) {
    (void)in_sizes; (void)n_in; (void)out_size; (void)ws_size;
    const void* x  = d_in[0];
    const void* Wq = d_in[1]; const void* bq = d_in[2];
    const void* Wk = d_in[3]; const void* bk = d_in[4];
    const void* Wv = d_in[5]; const void* bv = d_in[6];
    const void* Wo = d_in[7]; const void* bo = d_in[8];
    const void* pad = d_in[9];

    char* p = (char*)d_ws;
    auto alloc = [&](size_t bytes) { char* r = p; p += (bytes + 255) & ~(size_t)255; return r; };
    int*  flags = (int*)alloc(256);
    u16*  xb   = (u16*)alloc(2097152);
    u16*  Wqb  = (u16*)alloc(262144);
    u16*  Wkb  = (u16*)alloc(262144);
    u16*  Wvb  = (u16*)alloc(262144);
    u16*  Wob  = (u16*)alloc(262144);
    u16*  bqb  = (u16*)alloc(2048);
    u16*  bkb  = (u16*)alloc(2048);
    u16*  bvb  = (u16*)alloc(2048);
    u16*  bob  = (u16*)alloc(256);
    unsigned* mbits = (unsigned*)alloc(524288);
    float* lsum = (float*)alloc(262144);
    u16*  qb   = (u16*)alloc(16777216);
    u16*  kb   = (u16*)alloc(16777216);
    u16*  vtb  = (u16*)alloc(16777216);
    u16*  E    = (u16*)alloc(67108864);
    u16*  att  = qb;   // alias: qb last read in k2, att written in k4

    k0_detect<<<1, 256, 0, stream>>>((const unsigned*)pad, (const unsigned*)x, flags);
    kprep_conv8<<<(PREP_G8 + 255) / 256, 256, 0, stream>>>(
        x, Wq, bq, Wk, bk, Wv, bv, Wo, bo, flags,
        xb, Wqb, Wkb, Wvb, Wob, bqb, bkb, bvb, bob);
    kprep_mask<<<512, 256, 0, stream>>>(pad, flags, mbits, lsum);
    k1_proj<<<dim3(8, 64, 3), 256, 0, stream>>>(
        xb, Wqb, Wkb, Wvb, bqb, bkb, bvb, qb, kb, vtb);
    k2_escore<<<dim3(128, 4, 4), 256, 0, stream>>>(qb, kb, mbits, E, lsum);
    k3_vscale<<<4096, 256, 0, stream>>>(vtb, lsum);
    k4_av<<<dim3(128, 8), 256, 0, stream>>>(E, vtb, att);
    k5_out<<<dim3(2, 256), 256, 0, stream>>>(att, Wob, bob, flags, d_out);
}